// Round 8
// baseline (367.413 us; speedup 1.0000x reference)
//
#include <hip/hip_runtime.h>

// ---------------------------------------------------------------------------
// Cascade MLP, MI355X. fp16 hi/lo split GEMMs on MFMA (3 passes, fp32 accum).
// k-OCTET mapping: lane (l15,g) holds k in [8g,8g+8) for A and B. Rows store
// [hi-plane][lo-plane] -> one fragment == one ds_read_b128.
// Round-8 restructure: TWO kernels with proper occupancy shapes.
//  p1_k: 512 blk x 512 thr, LDS 72KB -> 2 blocks/CU (4 waves/SIMD), one
//        round, HBM-bound x stream; h1 -> ws (L3-resident, 34.6 MB).
//  p2_k: 512 blk x 512 thr, h in LDS, 3-buf counted-vmcnt ring, biases in
//        LDS; 2 waves/SIMD.
// ---------------------------------------------------------------------------

typedef __fp16 h2  __attribute__((ext_vector_type(2)));
typedef __fp16 h8v __attribute__((ext_vector_type(8)));
typedef float  f4v __attribute__((ext_vector_type(4)));

#define CHUNK 20480   // global W chunk stride (18432 used: 128 rows x 144 B)
#define LCH   24576   // LDS chunk buffer stride (3 x 16B x 512 thr staged)
#define WROW  144     // weight row: [hi 64B][lo 64B][pad 16B]
#define HROW  528     // h row: [hi 256B][lo 256B][pad 16B]
#define WOCH  20480   // head chunk stride (8448 used: 16 rows x 528 B)
#define HTILE 67584   // h tile: 128 * HROW

static constexpr unsigned OFF_W1  = 0;                       // 96 chunks
static constexpr unsigned OFF_WH  = 96u * CHUNK;             // 56 chunks
static constexpr unsigned OFF_WO  = OFF_WH + 56u * CHUNK;    // 3 head chunks
static constexpr unsigned OFF_BIN = OFF_WO + 3u * WOCH;      // 128 f32
static constexpr unsigned OFF_BH  = OFF_BIN + 512;           // 14 x 128 f32
static constexpr unsigned OFF_BO  = OFF_BIN + 7680;          // 3 x 16 f32
static constexpr unsigned OFF_H1  = OFF_BIN + 8192;          // 512 x HTILE

__device__ __forceinline__ unsigned bc2(h2 v) { return __builtin_bit_cast(unsigned, v); }

__device__ __forceinline__ f4v ntld4(const float* p) {
  return __builtin_nontemporal_load((const f4v*)p);
}

__device__ __forceinline__ void lds_cp16(const char* g, char* l) {
  __builtin_amdgcn_global_load_lds(
      (const __attribute__((address_space(1))) void*)g,
      (__attribute__((address_space(3))) void*)l, 16, 0, 0);
}

// stage 24576 B with 512 threads (3 x 16B each); reads up to 4 KB past the
// 20480-stride global chunk -- always within ws (weights/bias region).
__device__ __forceinline__ void stage3(const char* g, char* l, int tid) {
#pragma unroll
  for (int i = 0; i < 3; ++i) lds_cp16(g + i * 8192 + tid * 16, l + i * 8192 + tid * 16);
}

__device__ __forceinline__ void cvt8(f4v a, f4v b, h8v& hi, h8v& lo) {
  h2 h0 = __builtin_amdgcn_cvt_pkrtz(a[0], a[1]);
  h2 h1 = __builtin_amdgcn_cvt_pkrtz(a[2], a[3]);
  h2 h2_ = __builtin_amdgcn_cvt_pkrtz(b[0], b[1]);
  h2 h3 = __builtin_amdgcn_cvt_pkrtz(b[2], b[3]);
  h2 l0 = __builtin_amdgcn_cvt_pkrtz(a[0] - (float)h0[0], a[1] - (float)h0[1]);
  h2 l1 = __builtin_amdgcn_cvt_pkrtz(a[2] - (float)h1[0], a[3] - (float)h1[1]);
  h2 l2 = __builtin_amdgcn_cvt_pkrtz(b[0] - (float)h2_[0], b[1] - (float)h2_[1]);
  h2 l3 = __builtin_amdgcn_cvt_pkrtz(b[2] - (float)h3[0], b[3] - (float)h3[1]);
  hi = h8v{h0[0], h0[1], h1[0], h1[1], h2_[0], h2_[1], h3[0], h3[1]};
  lo = h8v{l0[0], l0[1], l1[0], l1[1], l2[0], l2[1], l3[0], l3[1]};
}

__device__ __forceinline__ void split_store(f4v v, char* hip, char* lop) {
  h2 a = __builtin_amdgcn_cvt_pkrtz(v[0], v[1]);
  h2 b = __builtin_amdgcn_cvt_pkrtz(v[2], v[3]);
  h2 c = __builtin_amdgcn_cvt_pkrtz(v[0] - (float)a[0], v[1] - (float)a[1]);
  h2 d = __builtin_amdgcn_cvt_pkrtz(v[2] - (float)b[0], v[3] - (float)b[1]);
  *(uint2*)hip = make_uint2(bc2(a), bc2(b));
  *(uint2*)lop = make_uint2(bc2(c), bc2(d));
}

__device__ __forceinline__ void split8w(const float* f, uint4& hi, uint4& lo) {
  h2 h0 = __builtin_amdgcn_cvt_pkrtz(f[0], f[1]);
  h2 h1 = __builtin_amdgcn_cvt_pkrtz(f[2], f[3]);
  h2 h2_ = __builtin_amdgcn_cvt_pkrtz(f[4], f[5]);
  h2 h3 = __builtin_amdgcn_cvt_pkrtz(f[6], f[7]);
  h2 l0 = __builtin_amdgcn_cvt_pkrtz(f[0] - (float)h0[0], f[1] - (float)h0[1]);
  h2 l1 = __builtin_amdgcn_cvt_pkrtz(f[2] - (float)h1[0], f[3] - (float)h1[1]);
  h2 l2 = __builtin_amdgcn_cvt_pkrtz(f[4] - (float)h2_[0], f[5] - (float)h2_[1]);
  h2 l3 = __builtin_amdgcn_cvt_pkrtz(f[6] - (float)h3[0], f[7] - (float)h3[1]);
  hi = make_uint4(bc2(h0), bc2(h1), bc2(h2_), bc2(h3));
  lo = make_uint4(bc2(l0), bc2(l1), bc2(l2), bc2(l3));
}

// flat items: L0-3=0..15, head0=16, L4-8=17..36, head1=37, L9-13=38..57, head2=58
__device__ __forceinline__ unsigned item_off(int it) {
  if (it >= 58) return OFF_WO + 2u * WOCH;   // 58 + dummy tails
  if (it == 16) return OFF_WO;
  if (it == 37) return OFF_WO + WOCH;
  int j = it - (it > 16 ? 1 : 0) - (it > 37 ? 1 : 0);
  return OFF_WH + (unsigned)j * CHUNK;
}

// ---------------------------------------------------------------------------
__global__ __launch_bounds__(256) void prep_k(
    const float* __restrict__ w_in, const float* __restrict__ b_in,
    const float* __restrict__ w_hid, const float* __restrict__ b_hid,
    const float* __restrict__ w_out, const float* __restrict__ b_out,
    char* __restrict__ ws) {
  int idx = blockIdx.x * 256 + threadIdx.x;
  float f[8];
  uint4 hi, lo;
  if (idx < 49152) {  // W1: c(96) x q(4) x n(128); k = c*32 + q*8 + j
    int n = idx & 127, cq = idx >> 7, q = cq & 3, c = cq >> 2;
    int k0 = c * 32 + q * 8;
#pragma unroll
    for (int j = 0; j < 8; ++j) f[j] = (n < 100) ? w_in[(size_t)(k0 + j) * 100 + n] : 0.f;
    split8w(f, hi, lo);
    char* dst = ws + OFF_W1 + (size_t)c * CHUNK + n * WROW + q * 16;
    *(uint4*)dst = hi;
    *(uint4*)(dst + 64) = lo;
    return;
  }
  idx -= 49152;
  if (idx < 28672) {  // WH: ch(56) x q(4) x n(128); k = s*32 + q*8 + j
    int n = idx & 127, cq = idx >> 7, q = cq & 3, ch = cq >> 2;
    int L = ch >> 2, s = ch & 3;
    int k0 = s * 32 + q * 8;
#pragma unroll
    for (int j = 0; j < 8; ++j) {
      int k = k0 + j;
      f[j] = (k < 100 && n < 100) ? w_hid[(size_t)L * 10000 + k * 100 + n] : 0.f;
    }
    split8w(f, hi, lo);
    char* dst = ws + OFF_WH + (size_t)ch * CHUNK + n * WROW + q * 16;
    *(uint4*)dst = hi;
    *(uint4*)(dst + 64) = lo;
    return;
  }
  idx -= 28672;
  if (idx < 768) {  // WO: st(3) x q(16) x l(16); HROW rows, full 128-k planes
    int l = idx & 15, sq = idx >> 4, q = sq & 15, st = sq >> 4;
    int k0 = q * 8;
#pragma unroll
    for (int j = 0; j < 8; ++j) {
      int k = k0 + j;
      f[j] = (k < 100 && l < 10) ? w_out[(size_t)st * 1000 + k * 10 + l] : 0.f;
    }
    split8w(f, hi, lo);
    char* dst = ws + OFF_WO + (size_t)st * WOCH + l * HROW + q * 16;
    *(uint4*)dst = hi;
    *(uint4*)(dst + 256) = lo;
    return;
  }
  idx -= 768;
  if (idx < 128) { ((float*)(ws + OFF_BIN))[idx] = (idx < 100) ? b_in[idx] : 0.f; return; }
  idx -= 128;
  if (idx < 1792) {
    int L = idx >> 7, n = idx & 127;
    ((float*)(ws + OFF_BH))[idx] = (n < 100) ? b_hid[L * 100 + n] : 0.f;
    return;
  }
  idx -= 1792;
  if (idx < 48) {
    int st = idx >> 4, n = idx & 15;
    ((float*)(ws + OFF_BO))[idx] = (n < 10) ? b_out[st * 10 + n] : -1e30f;
    return;
  }
}

// ---------------------------------------------------------------------------
// p1_k: h1 = relu(x @ w_in + b_in) -> ws H1 region. 8 waves x 16 rows.
// ---------------------------------------------------------------------------
#define P1_SMEM (3 * LCH)  // 73728 -> 2 blocks/CU

__global__ __launch_bounds__(512, 4) void p1_k(const float* __restrict__ x,
                                               char* __restrict__ ws) {
  extern __shared__ __align__(16) char sm[];
  const int tid = threadIdx.x;
  const int lane = tid & 63, wid = tid >> 6;
  const int l15 = lane & 15, g = lane >> 4;
  const int tile = blockIdx.x;
  const char* w1g = ws + OFF_W1;

  const float* xr = x + (size_t)(tile * 128 + wid * 16 + l15) * 3072;

  f4v xaP[2], xaQ[2];
  // prologue FIFO: stage(0)3, x(0)2, stage(1)3, x(1)2
  stage3(w1g, sm, tid);
  __builtin_amdgcn_sched_barrier(0);
  xaP[0] = ntld4(xr + g * 8); xaP[1] = ntld4(xr + g * 8 + 4);
  __builtin_amdgcn_sched_barrier(0);
  stage3(w1g + CHUNK, sm + LCH, tid);
  __builtin_amdgcn_sched_barrier(0);
  xaQ[0] = ntld4(xr + 32 + g * 8); xaQ[1] = ntld4(xr + 32 + g * 8 + 4);
  __builtin_amdgcn_sched_barrier(0);

  f4v z = {0.f, 0.f, 0.f, 0.f};
  f4v acc[8];
#pragma unroll
  for (int mf = 0; mf < 8; ++mf) acc[mf] = z;

  const int abase = l15 * WROW + g * 16;

  // steady state at top(s): outstanding = [stage(s)3, x(s)2, stage(s+1)3,
  // x(s+1)2] -> vmcnt(5) drains stage(s)+x(s).
  auto step = [&](int s, f4v (&xa)[2]) {
    if (s == 95) asm volatile("s_waitcnt vmcnt(0)" ::: "memory");
    else         asm volatile("s_waitcnt vmcnt(5)" ::: "memory");
    __builtin_amdgcn_s_barrier();
    asm volatile("" ::: "memory");

    h8v bhi, blo;
    cvt8(xa[0], xa[1], bhi, blo);
    if (s + 2 < 96) {
      stage3(w1g + (size_t)(s + 2) * CHUNK, sm + ((s + 2) % 3) * LCH, tid);
      const int o = (s + 2) * 32 + g * 8;
      xa[0] = ntld4(xr + o); xa[1] = ntld4(xr + o + 4);
    }
    __builtin_amdgcn_sched_barrier(0);

    const char* ab = sm + (s % 3) * LCH + abase;
#pragma unroll
    for (int mf = 0; mf < 8; ++mf) {
      const char* pa = ab + mf * (16 * WROW);
      h8v ahi = *(const h8v*)pa;
      h8v alo = *(const h8v*)(pa + 64);
      acc[mf] = __builtin_amdgcn_mfma_f32_16x16x32_f16(ahi, bhi, acc[mf], 0, 0, 0);
      acc[mf] = __builtin_amdgcn_mfma_f32_16x16x32_f16(ahi, blo, acc[mf], 0, 0, 0);
      acc[mf] = __builtin_amdgcn_mfma_f32_16x16x32_f16(alo, bhi, acc[mf], 0, 0, 0);
    }
  };

#pragma unroll 1
  for (int s2 = 0; s2 < 96; s2 += 2) {
    step(s2, xaP);
    step(s2 + 1, xaQ);
  }

  // epilogue: FIFO empty; bias, relu, split -> global h tile
  f4v bin[8];
  {
    const float* bp = (const float*)(ws + OFF_BIN) + g * 4;
#pragma unroll
    for (int mf = 0; mf < 8; ++mf) bin[mf] = *(const f4v*)(bp + mf * 16);
  }
  char* hg = ws + OFF_H1 + (size_t)tile * HTILE + (size_t)(wid * 16 + l15) * HROW;
#pragma unroll
  for (int mf = 0; mf < 8; ++mf) {
    f4v v = acc[mf] + bin[mf];
    v[0] = fmaxf(v[0], 0.f); v[1] = fmaxf(v[1], 0.f);
    v[2] = fmaxf(v[2], 0.f); v[3] = fmaxf(v[3], 0.f);
    split_store(v, hg + mf * 32 + g * 8, hg + 256 + mf * 32 + g * 8);
  }
}

// ---------------------------------------------------------------------------
// p2_k: 14-layer cascade + 3 heads + early-exit select. 8 waves:
// mr = wid>>2 (feature half), nc = wid&3 (row quarter, 32 rows).
// ---------------------------------------------------------------------------
#define P2_SMEM (HTILE + 3 * LCH + 8192)  // 67584 + 73728 + 8192 = 149504

__global__ __launch_bounds__(512, 2) void p2_k(char* __restrict__ ws,
                                               float* __restrict__ out) {
  extern __shared__ __align__(16) char sm[];
  char* smh = sm;                       // h tile
  char* smw = sm + HTILE;               // 3 chunk bufs
  char* smb = sm + HTILE + 3 * LCH;     // biases (BIN@0, BH@512, BO@7680)

  const int tid = threadIdx.x;
  const int lane = tid & 63, wid = tid >> 6;
  const int mr = wid >> 2, nc = wid & 3;
  const int l15 = lane & 15, g = lane >> 4;
  const int tile = blockIdx.x;

  f4v z = {0.f, 0.f, 0.f, 0.f};

  // prologue DMA: h tile (8 + cond), biases (1), stage items 0,1
  {
    const char* hg = ws + OFF_H1 + (size_t)tile * HTILE;
#pragma unroll
    for (int i = 0; i < 8; ++i) lds_cp16(hg + i * 8192 + tid * 16, smh + i * 8192 + tid * 16);
    if (tid < 128) lds_cp16(hg + 65536 + tid * 16, smh + 65536 + tid * 16);
    lds_cp16((const char*)ws + OFF_BIN + tid * 16, smb + tid * 16);
    __builtin_amdgcn_sched_barrier(0);
    stage3(ws + item_off(0), smw, tid);
    stage3(ws + item_off(1), smw + LCH, tid);
  }

  f4v acc[4][2] = {{z, z}, {z, z}, {z, z}, {z, z}};
  f4v o0[2], o1[2], o2[2];
  unsigned conf = 0;

  // ring: wait stage(i) done (leaves stage(i+1)) -> barrier -> stage(i+2).
  // stage(i+2) targets buf (i+2)%3 == (i-1)%3, whose readers finished before
  // the barrier at top(i). First wait also drains the prologue h/bias DMA.
  auto ring_top = [&](int i) {
    asm volatile("s_waitcnt vmcnt(3)" ::: "memory");
    __builtin_amdgcn_s_barrier();
    asm volatile("" ::: "memory");
    stage3(ws + item_off(i + 2), smw + ((i + 2) % 3) * LCH, tid);
  };

  auto hidden = [&](int base, int L) {
#pragma unroll
    for (int ss = 0; ss < 4; ++ss) {
      const int it = base + ss;
      ring_top(it);
      const char* wb = smw + (it % 3) * LCH + g * 16;
      const char* hb = smh + ss * 64 + g * 16;
      h8v bhi[2], blo[2];
#pragma unroll
      for (int nf = 0; nf < 2; ++nf) {
        const char* p = hb + (nc * 32 + nf * 16 + l15) * HROW;
        bhi[nf] = *(const h8v*)p;
        blo[nf] = *(const h8v*)(p + 256);
      }
#pragma unroll
      for (int mf = 0; mf < 4; ++mf) {
        const char* pa = wb + (mr * 64 + mf * 16 + l15) * WROW;
        h8v ahi = *(const h8v*)pa;
        h8v alo = *(const h8v*)(pa + 64);
#pragma unroll
        for (int nf = 0; nf < 2; ++nf) {
          acc[mf][nf] = __builtin_amdgcn_mfma_f32_16x16x32_f16(ahi, bhi[nf], acc[mf][nf], 0, 0, 0);
          acc[mf][nf] = __builtin_amdgcn_mfma_f32_16x16x32_f16(ahi, blo[nf], acc[mf][nf], 0, 0, 0);
          acc[mf][nf] = __builtin_amdgcn_mfma_f32_16x16x32_f16(alo, bhi[nf], acc[mf][nf], 0, 0, 0);
        }
      }
    }
    // epilogue: barrier (reads of old h done) -> bias+relu+split -> barrier
    __builtin_amdgcn_s_barrier();
    asm volatile("" ::: "memory");
    const float* bh = (const float*)(smb + 512) + L * 128 + mr * 64 + g * 4;
#pragma unroll
    for (int mf = 0; mf < 4; ++mf) {
      f4v bi = *(const f4v*)(bh + mf * 16);
#pragma unroll
      for (int nf = 0; nf < 2; ++nf) {
        f4v v = acc[mf][nf] + bi;
        v[0] = fmaxf(v[0], 0.f); v[1] = fmaxf(v[1], 0.f);
        v[2] = fmaxf(v[2], 0.f); v[3] = fmaxf(v[3], 0.f);
        char* hrow = smh + (nc * 32 + nf * 16 + l15) * HROW;
        split_store(v, hrow + mr * 128 + mf * 32 + g * 8,
                    hrow + 256 + mr * 128 + mf * 32 + g * 8);
        acc[mf][nf] = z;
      }
    }
    asm volatile("s_waitcnt lgkmcnt(0)" ::: "memory");
    __builtin_amdgcn_s_barrier();
    asm volatile("" ::: "memory");
  };

  auto wstage = [&](int i, f4v (&o)[2], int st, int shift) {
    ring_top(i);
    const char* wb = smw + (i % 3) * LCH;
    if (mr == 0) {  // 4 waves (nc = 0..3), wave-uniform branch
      f4v oa[2] = {z, z};
#pragma unroll
      for (int ss = 0; ss < 4; ++ss) {
        const char* pa = wb + l15 * HROW + ss * 64 + g * 16;
        h8v ahi = *(const h8v*)pa;
        h8v alo = *(const h8v*)(pa + 256);
#pragma unroll
        for (int nf = 0; nf < 2; ++nf) {
          const char* pb = smh + (nc * 32 + nf * 16 + l15) * HROW + ss * 64 + g * 16;
          h8v bhi = *(const h8v*)pb;
          h8v blo = *(const h8v*)(pb + 256);
          oa[nf] = __builtin_amdgcn_mfma_f32_16x16x32_f16(ahi, bhi, oa[nf], 0, 0, 0);
          oa[nf] = __builtin_amdgcn_mfma_f32_16x16x32_f16(ahi, blo, oa[nf], 0, 0, 0);
          oa[nf] = __builtin_amdgcn_mfma_f32_16x16x32_f16(alo, bhi, oa[nf], 0, 0, 0);
        }
      }
      f4v bi = *(const f4v*)((const float*)(smb + 7680) + st * 16 + g * 4);
#pragma unroll
      for (int nf = 0; nf < 2; ++nf) {
        oa[nf] += bi;  // padded classes carry bias -1e30
        float m = fmaxf(fmaxf(oa[nf][0], oa[nf][1]), fmaxf(oa[nf][2], oa[nf][3]));
        m = fmaxf(m, __shfl_xor(m, 16, 64));
        m = fmaxf(m, __shfl_xor(m, 32, 64));
        if (m > 0.5f) conf |= 1u << (shift + nf);
        o[nf] = oa[nf];
      }
    }
  };

  hidden(0, 0);
  hidden(4, 1);
  hidden(8, 2);
  hidden(12, 3);
  wstage(16, o0, 0, 0);
  hidden(17, 4);
  hidden(21, 5);
  hidden(25, 6);
  hidden(29, 7);
  hidden(33, 8);
  wstage(37, o1, 1, 2);
  hidden(38, 9);
  hidden(42, 10);
  hidden(46, 11);
  hidden(50, 12);
  hidden(54, 13);
  wstage(58, o2, 2, 4);

  if (mr == 0) {  // early-exit select + store (rows nc*32 + nf*16 + l15)
#pragma unroll
    for (int nf = 0; nf < 2; ++nf) {
      bool c0 = (conf >> (0 + nf)) & 1u, c1 = (conf >> (2 + nf)) & 1u;
      f4v r;
#pragma unroll
      for (int j = 0; j < 4; ++j) r[j] = c0 ? o0[nf][j] : (c1 ? o1[nf][j] : o2[nf][j]);
      float* dp = out + (size_t)(tile * 128 + nc * 32 + nf * 16 + l15) * 10;
      if (g == 0) {
        *(float2*)(dp) = make_float2(r[0], r[1]);
        *(float2*)(dp + 2) = make_float2(r[2], r[3]);
      } else if (g == 1) {
        *(float2*)(dp + 4) = make_float2(r[0], r[1]);
        *(float2*)(dp + 6) = make_float2(r[2], r[3]);
      } else if (g == 2) {
        *(float2*)(dp + 8) = make_float2(r[0], r[1]);
      }
    }
  }
}

// ---------------------------------------------------------------------------
extern "C" void kernel_launch(void* const* d_in, const int* in_sizes, int n_in,
                              void* d_out, int out_size, void* d_ws, size_t ws_size,
                              hipStream_t stream) {
  (void)in_sizes; (void)n_in; (void)out_size; (void)ws_size;
  const float* x     = (const float*)d_in[0];
  const float* w_in  = (const float*)d_in[1];
  const float* b_in  = (const float*)d_in[2];
  const float* w_hid = (const float*)d_in[3];
  const float* b_hid = (const float*)d_in[4];
  const float* w_out = (const float*)d_in[5];
  const float* b_out = (const float*)d_in[6];
  float* out = (float*)d_out;
  char* ws = (char*)d_ws;

  (void)hipFuncSetAttribute((const void*)p1_k,
                            hipFuncAttributeMaxDynamicSharedMemorySize, P1_SMEM);
  (void)hipFuncSetAttribute((const void*)p2_k,
                            hipFuncAttributeMaxDynamicSharedMemorySize, P2_SMEM);

  prep_k<<<315, 256, 0, stream>>>(w_in, b_in, w_hid, b_hid, w_out, b_out, ws);
  p1_k<<<512, 512, P1_SMEM, stream>>>(x, ws);
  p2_k<<<512, 512, P2_SMEM, stream>>>(ws, out);
}